// Round 2
// baseline (234.334 us; speedup 1.0000x reference)
//
#include <hip/hip_runtime.h>
#include <stdint.h>

#define B_ 8
#define N_ 4096
#define C_ 512
#define H_ 256
#define NC_ 1000

typedef float v4f __attribute__((ext_vector_type(4)));
typedef short v8s __attribute__((ext_vector_type(8)));
typedef unsigned short ushort_t;

__device__ __forceinline__ uint32_t f2bf1(float f) {
    uint32_t u = __float_as_uint(f);
    return (u + 0x7FFFu + ((u >> 16) & 1u)) >> 16;
}
__device__ __forceinline__ uint32_t pk2(float lo, float hi) {
#if __has_builtin(__builtin_amdgcn_cvt_pk_bf16_f32)
    auto r = __builtin_amdgcn_cvt_pk_bf16_f32(lo, hi);   // v_cvt_pk_bf16_f32
    return __builtin_bit_cast(uint32_t, r);
#else
    return f2bf1(lo) | (f2bf1(hi) << 16);
#endif
}

// ---- prep: inverse permutation + proj_W -> bf16 B-fragment order + zero pooled
// Wfrag (uint4 units): slot[(ntile*16 + kb)*64 + q*16 + c] holds
// bf16(W[ntile*16+c][kb*32 + q*8 + j]), j=0..7.  (exact 524288 B)
__global__ void prep_kernel(const float* __restrict__ ps, const float* __restrict__ W,
                            int* __restrict__ inv, ushort_t* __restrict__ Wfrag,
                            float* __restrict__ pooled) {
    int blk = blockIdx.x, t = threadIdx.x;
    if (blk == 0) {  // zero pooled (gemm accumulates with atomics)
        float4 z = {0.f, 0.f, 0.f, 0.f};
#pragma unroll
        for (int i = 0; i < 4; i++) ((float4*)pooled)[t * 4 + i] = z;
    }
    if (blk < 128) {
        int gid = blk * 256 + t;                       // 0..32767 = b*4096 + j
        float2 p = ((const float2*)ps)[gid];
        int key = (int)(p.x + 0.5f) + 64 * (int)(p.y + 0.5f);
        int b = gid >> 12;
        inv[(b << 12) + key] = gid & 4095;             // g[b, key] = feat[b, j]
    } else {
        int i = (blk - 128) * 256 + t;                 // 0..32767 = d*64 + kb*4 + q
        int d = i >> 6, kb = (i >> 2) & 15, q = i & 3;
        const float4* src = (const float4*)(W + d * C_ + kb * 32 + q * 8);
        float4 v0 = src[0], v1 = src[1];
        uint4 pk;
        pk.x = pk2(v0.x, v0.y); pk.y = pk2(v0.z, v0.w);
        pk.z = pk2(v1.x, v1.y); pk.w = pk2(v1.z, v1.w);
        ((uint4*)Wfrag)[((d >> 4) * 16 + kb) * 64 + q * 16 + (d & 15)] = pk;
    }
}

// ---- fused gather+GEMM+bias+LN+col-pool (512 gemm blocks) + prev-pool
// (512 prev blocks). Grid = 1024 = exactly 2 clean residency rounds at
// 2 blocks/CU; roles alternate bid&1 so each CU overlaps one memory-heavy
// prev block with one MFMA gemm block. Prev role is ILP-restructured:
// float4 loads in two register batches of 8 (2 latency exposures, not 32).
__global__ __launch_bounds__(512, 4)
void gemm_ln_pool(const float* __restrict__ feat, const float* __restrict__ prev,
                  const int* __restrict__ inv, const ushort_t* __restrict__ Wfrag,
                  const float* __restrict__ pb, const float* __restrict__ lg,
                  const float* __restrict__ lb, float* __restrict__ pooled) {
    __shared__ v8s Abuf[4096];          // 64 rows x 64 chunks(16B), xor-swizzled
    __shared__ float RowS[64], RowQ[64], ColS[512];

    const int bid = blockIdx.x;
    const int t = threadIdx.x;
    const int idx = bid >> 1;                           // 0..511
    const int b = idx >> 6;
    const int row0 = (idx & 63) << 6;

    if (bid & 1) {
        // ---- prev-pool role: column sums of this 64-row slab ----
        // thread t: float4-column (t&127), rows rg*16..rg*16+15 (rg = t>>7)
        const int col4 = t & 127, rg = t >> 7;
        const v4f* p = (const v4f*)prev +
                       (size_t)(b * N_ + row0 + rg * 16) * 128 + col4;
        v4f v[8];
        v4f s0 = {0.f, 0.f, 0.f, 0.f}, s1 = s0, s2 = s0, s3 = s0;
        // batch 0: rows 0..7 issued back-to-back (8 loads in flight)
#pragma unroll
        for (int r = 0; r < 8; r++) v[r] = p[r * 128];
#pragma unroll
        for (int r = 0; r < 8; r++) {
            if ((r & 3) == 0) s0 += v[r];
            else if ((r & 3) == 1) s1 += v[r];
            else if ((r & 3) == 2) s2 += v[r];
            else s3 += v[r];
        }
        // batch 1: rows 8..15
#pragma unroll
        for (int r = 0; r < 8; r++) v[r] = p[(8 + r) * 128];
#pragma unroll
        for (int r = 0; r < 8; r++) {
            if ((r & 3) == 0) s0 += v[r];
            else if ((r & 3) == 1) s1 += v[r];
            else if ((r & 3) == 2) s2 += v[r];
            else s3 += v[r];
        }
        v4f s = (s0 + s1) + (s2 + s3);
        // combine the 4 rg-groups through LDS (ColS reused as scratch)
        ColS[t] = 0.f;
        __syncthreads();
        atomicAdd(&ColS[col4 * 4 + 0], s.x);
        atomicAdd(&ColS[col4 * 4 + 1], s.y);
        atomicAdd(&ColS[col4 * 4 + 2], s.z);
        atomicAdd(&ColS[col4 * 4 + 3], s.w);
        __syncthreads();
        atomicAdd(&pooled[b * C_ + t], ColS[t]);
        return;
    }

    const int wv = t >> 6, lane = t & 63, c = lane & 15, q = lane >> 4;

    if (t < 64) { RowS[t] = 0.f; RowQ[t] = 0.f; }

    // ---- phase 1: stage full A tile (gather + fp32->bf16), 16 float4/thread ----
    const int arow = t >> 3;                           // 0..63
    const int acol8 = t & 7;
    const int grow = inv[(b << 12) + row0 + arow];
    const float* asrc = feat + ((size_t)(b * N_ + grow) * C_);
#pragma unroll 4
    for (int s = 0; s < 8; s++) {
        const int chunk = s * 8 + acol8;               // logical 16B-chunk 0..63
        float4 f0 = ((const float4*)asrc)[chunk * 2];
        float4 f1 = ((const float4*)asrc)[chunk * 2 + 1];
        uint4 pk;
        pk.x = pk2(f0.x, f0.y); pk.y = pk2(f0.z, f0.w);
        pk.z = pk2(f1.x, f1.y); pk.w = pk2(f1.z, f1.w);
        ((uint4*)Abuf)[arow * 64 + (chunk ^ (arow & 7))] = pk;
    }

    // B fragment bases: wave wv owns cols [64*wv, 64*wv+64), ntile = wv*4+nt
    const ushort_t* fb[4];
#pragma unroll
    for (int nt = 0; nt < 4; nt++)
        fb[nt] = Wfrag + (wv * 4 + nt) * 8192 + lane * 8;

    v4f acc[4][4];
    const v4f vzero = {0.f, 0.f, 0.f, 0.f};
#pragma unroll
    for (int mt = 0; mt < 4; mt++)
#pragma unroll
        for (int nt = 0; nt < 4; nt++) acc[mt][nt] = vzero;

    // kb=0 B prefetch issued before the barrier (L2-hit, no LDS dependence)
    v8s bf[2][4], af[4];
#pragma unroll
    for (int nt = 0; nt < 4; nt++) bf[0][nt] = *((const v8s*)(fb[nt]));

    __syncthreads();

    // ---- phase 2: barrier-free K loop, 1-tile software pipeline on B.
    // Full unroll keeps every bf[cur] index compile-time (no scratch).
#pragma unroll
    for (int kb = 0; kb < 16; kb++) {
        const int cur = kb & 1;
        if (kb < 15) {
#pragma unroll
            for (int nt = 0; nt < 4; nt++)
                bf[cur ^ 1][nt] = *((const v8s*)(fb[nt] + (kb + 1) * 512));
        }
#pragma unroll
        for (int mt = 0; mt < 4; mt++)
            af[mt] = Abuf[(mt * 16 + c) * 64 + ((kb * 4 + q) ^ (c & 7))];
#pragma unroll
        for (int mt = 0; mt < 4; mt++)
#pragma unroll
            for (int nt = 0; nt < 4; nt++)
                acc[mt][nt] = __builtin_amdgcn_mfma_f32_16x16x32_bf16(
                    af[mt], bf[cur][nt], acc[mt][nt], 0, 0, 0);
    }

    // ---- epilogue: bias, LN row stats, normalize, column pool ----
    float pb4[4], lg4[4], lb4[4];
#pragma unroll
    for (int nt = 0; nt < 4; nt++) {
        int n = wv * 64 + nt * 16 + c;
        pb4[nt] = pb[n]; lg4[nt] = lg[n]; lb4[nt] = lb[n];
    }
#pragma unroll
    for (int mt = 0; mt < 4; mt++) {
#pragma unroll
        for (int reg = 0; reg < 4; reg++) {
            float s1 = 0.f, s2 = 0.f;
#pragma unroll
            for (int nt = 0; nt < 4; nt++) {
                float v = acc[mt][nt][reg] + pb4[nt];
                acc[mt][nt][reg] = v;
                s1 += v; s2 += v * v;
            }
#pragma unroll
            for (int d = 1; d < 16; d <<= 1) {
                s1 += __shfl_xor(s1, d);
                s2 += __shfl_xor(s2, d);
            }
            if (c == 0) {
                int r = mt * 16 + q * 4 + reg;
                atomicAdd(&RowS[r], s1);
                atomicAdd(&RowQ[r], s2);
            }
        }
    }
    __syncthreads();
    if (t < 64) {
        float mu = RowS[t] * (1.f / C_);
        float var = RowQ[t] * (1.f / C_) - mu * mu;
        RowS[t] = mu;
        RowQ[t] = rsqrtf(var + 1e-5f);
    }
    __syncthreads();
    float col[4] = {0.f, 0.f, 0.f, 0.f};
#pragma unroll
    for (int mt = 0; mt < 4; mt++) {
#pragma unroll
        for (int reg = 0; reg < 4; reg++) {
            int r = mt * 16 + q * 4 + reg;
            float mu = RowS[r], rs = RowQ[r];
#pragma unroll
            for (int nt = 0; nt < 4; nt++)
                col[nt] += (acc[mt][nt][reg] - mu) * rs * lg4[nt] + lb4[nt];
        }
    }
#pragma unroll
    for (int nt = 0; nt < 4; nt++) {
        col[nt] += __shfl_xor(col[nt], 16);
        col[nt] += __shfl_xor(col[nt], 32);
    }
    if (lane < 16) {
#pragma unroll
        for (int nt = 0; nt < 4; nt++) ColS[wv * 64 + nt * 16 + c] = col[nt];
    }
    __syncthreads();
    atomicAdd(&pooled[b * C_ + t], ColS[t]);
}

// ---- head: single kernel. Each block: redundant h1,h2 (per-thread row dots,
// W1/W2 L2-hot) then a 40-output slice of layer 3 (wave-per-output). ----------
__global__ __launch_bounds__(256)
void head_kernel(const float* __restrict__ pooled,
                 const float* __restrict__ W1, const float* __restrict__ b1,
                 const float* __restrict__ W2, const float* __restrict__ b2,
                 const float* __restrict__ W3, const float* __restrict__ b3,
                 float* __restrict__ out) {
    __shared__ __align__(16) float P[512];
    __shared__ __align__(16) float H1[256];
    __shared__ __align__(16) float H2[256];
    const int t = threadIdx.x, wv = t >> 6, lane = t & 63;
    const int b = blockIdx.x / 25;
    const int slice = blockIdx.x % 25;                 // 25 slices x 40 outputs

    P[t] = pooled[b * C_ + t] * (1.f / 4096.f);
    P[t + 256] = pooled[b * C_ + t + 256] * (1.f / 4096.f);
    __syncthreads();

    // h1[t] = relu(W1[t,:] . P + b1[t])   (128 independent float4 loads)
    {
        const float4* wr = (const float4*)(W1 + t * C_);
        float s = 0.f;
#pragma unroll 8
        for (int k = 0; k < 128; k++) {
            float4 w = wr[k];
            float4 p = ((const float4*)P)[k];
            s += w.x * p.x + w.y * p.y + w.z * p.z + w.w * p.w;
        }
        H1[t] = fmaxf(s + b1[t], 0.f);
    }
    __syncthreads();

    // h2[t] = relu(W2[t,:] . H1 + b2[t])
    {
        const float4* wr = (const float4*)(W2 + t * H_);
        float s = 0.f;
#pragma unroll 8
        for (int k = 0; k < 64; k++) {
            float4 w = wr[k];
            float4 p = ((const float4*)H1)[k];
            s += w.x * p.x + w.y * p.y + w.z * p.z + w.w * p.w;
        }
        H2[t] = fmaxf(s + b2[t], 0.f);
    }
    __syncthreads();

    // layer 3: this block's 40 outputs, wave-per-output (coalesced W3 row)
#pragma unroll
    for (int jj = 0; jj < 10; jj++) {
        const int o = slice * 40 + jj * 4 + wv;
        float4 w = ((const float4*)(W3 + o * H_))[lane];
        float4 p = ((const float4*)H2)[lane];
        float s = w.x * p.x + w.y * p.y + w.z * p.z + w.w * p.w;
#pragma unroll
        for (int d = 1; d < 64; d <<= 1) s += __shfl_xor(s, d);
        if (lane == 0) out[b * NC_ + o] = s + b3[o];
    }
}

extern "C" void kernel_launch(void* const* d_in, const int* in_sizes, int n_in,
                              void* d_out, int out_size, void* d_ws, size_t ws_size,
                              hipStream_t stream) {
    const float* feat  = (const float*)d_in[0];
    const float* prev  = (const float*)d_in[1];
    // d_in[2] = pos_org (implicit: key(pos_org[n]) == n) — unused
    const float* ps    = (const float*)d_in[3];
    const float* projW = (const float*)d_in[4];
    const float* pb    = (const float*)d_in[5];
    const float* lg    = (const float*)d_in[6];
    const float* lb    = (const float*)d_in[7];
    const float* W1    = (const float*)d_in[8];
    const float* b1    = (const float*)d_in[9];
    const float* W2    = (const float*)d_in[10];
    const float* b2    = (const float*)d_in[11];
    const float* W3    = (const float*)d_in[12];
    const float* b3    = (const float*)d_in[13];
    float* out = (float*)d_out;

    char* ws = (char*)d_ws;
    ushort_t* Wfrag = (ushort_t*)ws;                     // 524288 B (exact)
    int* inv        = (int*)(ws + 524288);               // 131072 B
    float* pooled   = (float*)(ws + 655360);             // 16384 B

    prep_kernel<<<256, 256, 0, stream>>>(ps, projW, inv, Wfrag, pooled);
    gemm_ln_pool<<<1024, 512, 0, stream>>>(feat, prev, inv, Wfrag,
                                           pb, lg, lb, pooled);
    head_kernel<<<200, 256, 0, stream>>>(pooled, W1, b1, W2, b2, W3, b3, out);
}

// Round 3
// 224.252 us; speedup vs baseline: 1.0450x; 1.0450x over previous
//
#include <hip/hip_runtime.h>
#include <stdint.h>

#define B_ 8
#define N_ 4096
#define C_ 512
#define H_ 256
#define NC_ 1000

typedef float v4f __attribute__((ext_vector_type(4)));
typedef short v8s __attribute__((ext_vector_type(8)));
typedef unsigned short ushort_t;

__device__ __forceinline__ uint32_t f2bf1(float f) {
    uint32_t u = __float_as_uint(f);
    return (u + 0x7FFFu + ((u >> 16) & 1u)) >> 16;
}
__device__ __forceinline__ uint32_t pk2(float lo, float hi) {
#if __has_builtin(__builtin_amdgcn_cvt_pk_bf16_f32)
    auto r = __builtin_amdgcn_cvt_pk_bf16_f32(lo, hi);   // v_cvt_pk_bf16_f32
    return __builtin_bit_cast(uint32_t, r);
#else
    return f2bf1(lo) | (f2bf1(hi) << 16);
#endif
}

// ---- prep: inverse permutation + proj_W -> bf16 B-fragment order + zero pooled
// Wfrag (uint4 units): slot[(ntile*16 + kb)*64 + q*16 + c] holds
// bf16(W[ntile*16+c][kb*32 + q*8 + j]), j=0..7.  (exact 524288 B)
__global__ void prep_kernel(const float* __restrict__ ps, const float* __restrict__ W,
                            int* __restrict__ inv, ushort_t* __restrict__ Wfrag,
                            float* __restrict__ pooled) {
    int blk = blockIdx.x, t = threadIdx.x;
    if (blk == 0) {  // zero pooled (gemm accumulates with atomics)
        float4 z = {0.f, 0.f, 0.f, 0.f};
#pragma unroll
        for (int i = 0; i < 4; i++) ((float4*)pooled)[t * 4 + i] = z;
    }
    if (blk < 128) {
        int gid = blk * 256 + t;                       // 0..32767 = b*4096 + j
        float2 p = ((const float2*)ps)[gid];
        int key = (int)(p.x + 0.5f) + 64 * (int)(p.y + 0.5f);
        int b = gid >> 12;
        inv[(b << 12) + key] = gid & 4095;             // g[b, key] = feat[b, j]
    } else {
        int i = (blk - 128) * 256 + t;                 // 0..32767 = d*64 + kb*4 + q
        int d = i >> 6, kb = (i >> 2) & 15, q = i & 3;
        const float4* src = (const float4*)(W + d * C_ + kb * 32 + q * 8);
        float4 v0 = src[0], v1 = src[1];
        uint4 pk;
        pk.x = pk2(v0.x, v0.y); pk.y = pk2(v0.z, v0.w);
        pk.z = pk2(v1.x, v1.y); pk.w = pk2(v1.z, v1.w);
        ((uint4*)Wfrag)[((d >> 4) * 16 + kb) * 64 + q * 16 + (d & 15)] = pk;
    }
}

// ---- fused gather+GEMM+bias+LN+col-pool (1024 gemm blocks, 32-row tiles)
// + prev-pool (512 blocks, 64-row slabs). Grid = 1536 = exactly 2 residency
// rounds at 3 blocks/CU. 32-row tile => Abuf 32KB, LDS 35KB (4-block LDS cap);
// launch_bounds(512,6) => 85-reg cap, est. ~82 used (32 acc + ~50 arch) =>
// 3 blocks/CU resident, +50% loads in flight vs the 68KB/2-block version.
// K-loop is the round-0 no-spill form: unroll 2, B loaded in-loop.
__global__ __launch_bounds__(512, 6)
void gemm_ln_pool(const float* __restrict__ feat, const float* __restrict__ prev,
                  const int* __restrict__ inv, const ushort_t* __restrict__ Wfrag,
                  const float* __restrict__ pb, const float* __restrict__ lg,
                  const float* __restrict__ lb, float* __restrict__ pooled) {
    __shared__ v8s Abuf[2048];          // 32 rows x 64 chunks(16B), xor-swizzled
    __shared__ float RowS[32], RowQ[32], ColS[512];

    const int bid = blockIdx.x;
    const int t = threadIdx.x;

    if (bid % 3 == 2) {
        // ---- prev-pool role: column sums of a 64-row slab, 8-deep MLP ----
        const int p = bid / 3;                          // 0..511
        const int b = p >> 6;
        const int r0 = (p & 63) << 6;                   // 64-row slab
        const float* psrc = prev + ((size_t)(b * N_ + r0) * C_) + t;
        float s0 = 0.f, s1 = 0.f, s2 = 0.f, s3 = 0.f;
        float s4 = 0.f, s5 = 0.f, s6 = 0.f, s7 = 0.f;
#pragma unroll
        for (int r = 0; r < 64; r += 8) {
            s0 += psrc[(r + 0) * C_];
            s1 += psrc[(r + 1) * C_];
            s2 += psrc[(r + 2) * C_];
            s3 += psrc[(r + 3) * C_];
            s4 += psrc[(r + 4) * C_];
            s5 += psrc[(r + 5) * C_];
            s6 += psrc[(r + 6) * C_];
            s7 += psrc[(r + 7) * C_];
        }
        atomicAdd(&pooled[b * C_ + t],
                  ((s0 + s1) + (s2 + s3)) + ((s4 + s5) + (s6 + s7)));
        return;
    }

    const int gix = (bid / 3) * 2 + (bid % 3);          // 0..1023
    const int b = gix >> 7;                             // 128 tiles per batch
    const int row0 = (gix & 127) << 5;                  // 32-row tile
    const int wv = t >> 6, lane = t & 63, c = lane & 15, q = lane >> 4;

    if (t < 32) { RowS[t] = 0.f; RowQ[t] = 0.f; }

    // ---- phase 1: stage 32-row A tile (gather + fp32->bf16), 8 float4/thread
    const int arow = t >> 4;                           // 0..31
    const int acol = t & 15;
    const int grow = inv[(b << 12) + row0 + arow];
    const float* asrc = feat + ((size_t)(b * N_ + grow) * C_);
#pragma unroll
    for (int s = 0; s < 4; s++) {
        const int chunk = s * 16 + acol;               // logical 16B-chunk 0..63
        float4 f0 = ((const float4*)asrc)[chunk * 2];
        float4 f1 = ((const float4*)asrc)[chunk * 2 + 1];
        uint4 pk;
        pk.x = pk2(f0.x, f0.y); pk.y = pk2(f0.z, f0.w);
        pk.z = pk2(f1.x, f1.y); pk.w = pk2(f1.z, f1.w);
        ((uint4*)Abuf)[arow * 64 + (chunk ^ (arow & 7))] = pk;
    }

    // B fragment bases: wave wv owns cols [64*wv, 64*wv+64), ntile = wv*4+nt
    const ushort_t* fb[4];
#pragma unroll
    for (int nt = 0; nt < 4; nt++)
        fb[nt] = Wfrag + (wv * 4 + nt) * 8192 + lane * 8;

    v4f acc[2][4];
    const v4f vzero = {0.f, 0.f, 0.f, 0.f};
#pragma unroll
    for (int mt = 0; mt < 2; mt++)
#pragma unroll
        for (int nt = 0; nt < 4; nt++) acc[mt][nt] = vzero;

    __syncthreads();

    // ---- phase 2: barrier-free K loop (round-0 form: no explicit pipeline,
    // unroll 2 gives the scheduler one iteration of lookahead within budget)
#pragma unroll 2
    for (int kb = 0; kb < 16; kb++) {
        v8s af[2], bf[4];
#pragma unroll
        for (int nt = 0; nt < 4; nt++)
            bf[nt] = *((const v8s*)(fb[nt] + kb * 512));
#pragma unroll
        for (int mt = 0; mt < 2; mt++)
            af[mt] = Abuf[(mt * 16 + c) * 64 + ((kb * 4 + q) ^ (c & 7))];
#pragma unroll
        for (int mt = 0; mt < 2; mt++)
#pragma unroll
            for (int nt = 0; nt < 4; nt++)
                acc[mt][nt] = __builtin_amdgcn_mfma_f32_16x16x32_bf16(
                    af[mt], bf[nt], acc[mt][nt], 0, 0, 0);
    }

    // ---- epilogue: bias, LN row stats, normalize, column pool ----
    float pb4[4], lg4[4], lb4[4];
#pragma unroll
    for (int nt = 0; nt < 4; nt++) {
        int n = wv * 64 + nt * 16 + c;
        pb4[nt] = pb[n]; lg4[nt] = lg[n]; lb4[nt] = lb[n];
    }
#pragma unroll
    for (int mt = 0; mt < 2; mt++) {
#pragma unroll
        for (int reg = 0; reg < 4; reg++) {
            float s1 = 0.f, s2 = 0.f;
#pragma unroll
            for (int nt = 0; nt < 4; nt++) {
                float v = acc[mt][nt][reg] + pb4[nt];
                acc[mt][nt][reg] = v;
                s1 += v; s2 += v * v;
            }
#pragma unroll
            for (int d = 1; d < 16; d <<= 1) {
                s1 += __shfl_xor(s1, d);
                s2 += __shfl_xor(s2, d);
            }
            if (c == 0) {
                int r = mt * 16 + q * 4 + reg;
                atomicAdd(&RowS[r], s1);
                atomicAdd(&RowQ[r], s2);
            }
        }
    }
    __syncthreads();
    if (t < 32) {
        float mu = RowS[t] * (1.f / C_);
        float var = RowQ[t] * (1.f / C_) - mu * mu;
        RowS[t] = mu;
        RowQ[t] = rsqrtf(var + 1e-5f);
    }
    __syncthreads();
    float col[4] = {0.f, 0.f, 0.f, 0.f};
#pragma unroll
    for (int mt = 0; mt < 2; mt++) {
#pragma unroll
        for (int reg = 0; reg < 4; reg++) {
            int r = mt * 16 + q * 4 + reg;
            float mu = RowS[r], rs = RowQ[r];
#pragma unroll
            for (int nt = 0; nt < 4; nt++)
                col[nt] += (acc[mt][nt][reg] - mu) * rs * lg4[nt] + lb4[nt];
        }
    }
#pragma unroll
    for (int nt = 0; nt < 4; nt++) {
        col[nt] += __shfl_xor(col[nt], 16);
        col[nt] += __shfl_xor(col[nt], 32);
    }
    if (lane < 16) {
#pragma unroll
        for (int nt = 0; nt < 4; nt++) ColS[wv * 64 + nt * 16 + c] = col[nt];
    }
    __syncthreads();
    atomicAdd(&pooled[b * C_ + t], ColS[t]);
}

// ---- head: single kernel. Each block: redundant h1,h2 (per-thread row dots,
// W1/W2 L2-hot) then a 40-output slice of layer 3 (wave-per-output). ----------
__global__ __launch_bounds__(256)
void head_kernel(const float* __restrict__ pooled,
                 const float* __restrict__ W1, const float* __restrict__ b1,
                 const float* __restrict__ W2, const float* __restrict__ b2,
                 const float* __restrict__ W3, const float* __restrict__ b3,
                 float* __restrict__ out) {
    __shared__ __align__(16) float P[512];
    __shared__ __align__(16) float H1[256];
    __shared__ __align__(16) float H2[256];
    const int t = threadIdx.x, wv = t >> 6, lane = t & 63;
    const int b = blockIdx.x / 25;
    const int slice = blockIdx.x % 25;                 // 25 slices x 40 outputs

    P[t] = pooled[b * C_ + t] * (1.f / 4096.f);
    P[t + 256] = pooled[b * C_ + t + 256] * (1.f / 4096.f);
    __syncthreads();

    // h1[t] = relu(W1[t,:] . P + b1[t])   (128 independent float4 loads)
    {
        const float4* wr = (const float4*)(W1 + t * C_);
        float s = 0.f;
#pragma unroll 8
        for (int k = 0; k < 128; k++) {
            float4 w = wr[k];
            float4 p = ((const float4*)P)[k];
            s += w.x * p.x + w.y * p.y + w.z * p.z + w.w * p.w;
        }
        H1[t] = fmaxf(s + b1[t], 0.f);
    }
    __syncthreads();

    // h2[t] = relu(W2[t,:] . H1 + b2[t])
    {
        const float4* wr = (const float4*)(W2 + t * H_);
        float s = 0.f;
#pragma unroll 8
        for (int k = 0; k < 64; k++) {
            float4 w = wr[k];
            float4 p = ((const float4*)H1)[k];
            s += w.x * p.x + w.y * p.y + w.z * p.z + w.w * p.w;
        }
        H2[t] = fmaxf(s + b2[t], 0.f);
    }
    __syncthreads();

    // layer 3: this block's 40 outputs, wave-per-output (coalesced W3 row)
#pragma unroll
    for (int jj = 0; jj < 10; jj++) {
        const int o = slice * 40 + jj * 4 + wv;
        float4 w = ((const float4*)(W3 + o * H_))[lane];
        float4 p = ((const float4*)H2)[lane];
        float s = w.x * p.x + w.y * p.y + w.z * p.z + w.w * p.w;
#pragma unroll
        for (int d = 1; d < 64; d <<= 1) s += __shfl_xor(s, d);
        if (lane == 0) out[b * NC_ + o] = s + b3[o];
    }
}

extern "C" void kernel_launch(void* const* d_in, const int* in_sizes, int n_in,
                              void* d_out, int out_size, void* d_ws, size_t ws_size,
                              hipStream_t stream) {
    const float* feat  = (const float*)d_in[0];
    const float* prev  = (const float*)d_in[1];
    // d_in[2] = pos_org (implicit: key(pos_org[n]) == n) — unused
    const float* ps    = (const float*)d_in[3];
    const float* projW = (const float*)d_in[4];
    const float* pb    = (const float*)d_in[5];
    const float* lg    = (const float*)d_in[6];
    const float* lb    = (const float*)d_in[7];
    const float* W1    = (const float*)d_in[8];
    const float* b1    = (const float*)d_in[9];
    const float* W2    = (const float*)d_in[10];
    const float* b2    = (const float*)d_in[11];
    const float* W3    = (const float*)d_in[12];
    const float* b3    = (const float*)d_in[13];
    float* out = (float*)d_out;

    char* ws = (char*)d_ws;
    ushort_t* Wfrag = (ushort_t*)ws;                     // 524288 B (exact)
    int* inv        = (int*)(ws + 524288);               // 131072 B
    float* pooled   = (float*)(ws + 655360);             // 16384 B

    prep_kernel<<<256, 256, 0, stream>>>(ps, projW, inv, Wfrag, pooled);
    gemm_ln_pool<<<1536, 512, 0, stream>>>(feat, prev, inv, Wfrag,
                                           pb, lg, lb, pooled);
    head_kernel<<<200, 256, 0, stream>>>(pooled, W1, b1, W2, b2, W3, b3, out);
}

// Round 4
// 217.716 us; speedup vs baseline: 1.0763x; 1.0300x over previous
//
#include <hip/hip_runtime.h>
#include <stdint.h>

#define B_ 8
#define N_ 4096
#define C_ 512
#define H_ 256
#define NC_ 1000

typedef float v4f __attribute__((ext_vector_type(4)));
typedef short v8s __attribute__((ext_vector_type(8)));
typedef unsigned short ushort_t;

__device__ __forceinline__ uint32_t f2bf1(float f) {
    uint32_t u = __float_as_uint(f);
    return (u + 0x7FFFu + ((u >> 16) & 1u)) >> 16;
}
__device__ __forceinline__ uint32_t pk2(float lo, float hi) {
#if __has_builtin(__builtin_amdgcn_cvt_pk_bf16_f32)
    auto r = __builtin_amdgcn_cvt_pk_bf16_f32(lo, hi);   // v_cvt_pk_bf16_f32
    return __builtin_bit_cast(uint32_t, r);
#else
    return f2bf1(lo) | (f2bf1(hi) << 16);
#endif
}

// ---- prep: inverse permutation + proj_W -> bf16 B-fragment order + zero pooled
// Wfrag (uint4 units): slot[(ntile*16 + kb)*64 + q*16 + c] holds
// bf16(W[ntile*16+c][kb*32 + q*8 + j]), j=0..7.  (exact 524288 B)
__global__ void prep_kernel(const float* __restrict__ ps, const float* __restrict__ W,
                            int* __restrict__ inv, ushort_t* __restrict__ Wfrag,
                            float* __restrict__ pooled) {
    int blk = blockIdx.x, t = threadIdx.x;
    if (blk == 0) {  // zero pooled (gemm accumulates with atomics)
        float4 z = {0.f, 0.f, 0.f, 0.f};
#pragma unroll
        for (int i = 0; i < 4; i++) ((float4*)pooled)[t * 4 + i] = z;
    }
    if (blk < 128) {
        int gid = blk * 256 + t;                       // 0..32767 = b*4096 + j
        float2 p = ((const float2*)ps)[gid];
        int key = (int)(p.x + 0.5f) + 64 * (int)(p.y + 0.5f);
        int b = gid >> 12;
        inv[(b << 12) + key] = gid & 4095;             // g[b, key] = feat[b, j]
    } else {
        int i = (blk - 128) * 256 + t;                 // 0..32767 = d*64 + kb*4 + q
        int d = i >> 6, kb = (i >> 2) & 15, q = i & 3;
        const float4* src = (const float4*)(W + d * C_ + kb * 32 + q * 8);
        float4 v0 = src[0], v1 = src[1];
        uint4 pk;
        pk.x = pk2(v0.x, v0.y); pk.y = pk2(v0.z, v0.w);
        pk.z = pk2(v1.x, v1.y); pk.w = pk2(v1.z, v1.w);
        ((uint4*)Wfrag)[((d >> 4) * 16 + kb) * 64 + q * 16 + (d & 15)] = pk;
    }
}

// ---- fused gather+GEMM+bias+LN+col-pool (512 blocks) + prev-pool (256 blocks)
// Round-0 structure (proven 60us). ONE change: all zero-reuse streams (feat
// gather, prev) use __builtin_nontemporal_load so they stop thrashing the
// 4MB per-XCD L2. Theory: Wfrag (512KB, re-read 512x = 256MB) then stays
// L2-resident and the K-loop's B loads become real L2 hits instead of L3
// round-trips contending with the streams.
__global__ __launch_bounds__(512, 4)
void gemm_ln_pool(const float* __restrict__ feat, const float* __restrict__ prev,
                  const int* __restrict__ inv, const ushort_t* __restrict__ Wfrag,
                  const float* __restrict__ pb, const float* __restrict__ lg,
                  const float* __restrict__ lb, float* __restrict__ pooled) {
    __shared__ v8s Abuf[4096];          // 64 rows x 64 chunks(16B), xor-swizzled
    __shared__ float RowS[64], RowQ[64], ColS[512];

    const int bid = blockIdx.x;
    const int t = threadIdx.x;

    if (bid % 3 == 2) {
        // ---- prev-pool role: column sums of 128 prev rows (nt streaming) ----
        const int p = bid / 3;                          // 0..255
        const int b = p >> 5;
        const int r0 = (p & 31) << 7;                   // 128-row slab
        const float* psrc = prev + ((size_t)(b * N_ + r0) * C_) + t;
        float s0 = 0.f, s1 = 0.f, s2 = 0.f, s3 = 0.f;
#pragma unroll 4
        for (int r = 0; r < 128; r += 4) {
            s0 += __builtin_nontemporal_load(&psrc[(r + 0) * C_]);
            s1 += __builtin_nontemporal_load(&psrc[(r + 1) * C_]);
            s2 += __builtin_nontemporal_load(&psrc[(r + 2) * C_]);
            s3 += __builtin_nontemporal_load(&psrc[(r + 3) * C_]);
        }
        atomicAdd(&pooled[b * C_ + t], (s0 + s1) + (s2 + s3));
        return;
    }

    const int gix = (bid / 3) * 2 + (bid % 3);          // 0..511
    const int b = gix >> 6;
    const int row0 = (gix & 63) << 6;
    const int wv = t >> 6, lane = t & 63, c = lane & 15, q = lane >> 4;

    if (t < 64) { RowS[t] = 0.f; RowQ[t] = 0.f; }

    // ---- phase 1: stage full A tile (gather + fp32->bf16), nt loads ----
    const int arow = t >> 3;                           // 0..63
    const int acol8 = t & 7;
    const int grow = inv[(b << 12) + row0 + arow];
    const v4f* asrc = (const v4f*)(feat + ((size_t)(b * N_ + grow) * C_));
#pragma unroll 4
    for (int s = 0; s < 8; s++) {
        const int chunk = s * 8 + acol8;               // logical 16B-chunk 0..63
        v4f f0 = __builtin_nontemporal_load(asrc + chunk * 2);
        v4f f1 = __builtin_nontemporal_load(asrc + chunk * 2 + 1);
        uint4 pk;
        pk.x = pk2(f0.x, f0.y); pk.y = pk2(f0.z, f0.w);
        pk.z = pk2(f1.x, f1.y); pk.w = pk2(f1.z, f1.w);
        ((uint4*)Abuf)[arow * 64 + (chunk ^ (arow & 7))] = pk;
    }

    // B fragment bases: wave wv owns cols [64*wv, 64*wv+64), ntile = wv*4+nt
    const ushort_t* fb[4];
#pragma unroll
    for (int nt = 0; nt < 4; nt++)
        fb[nt] = Wfrag + (wv * 4 + nt) * 8192 + lane * 8;

    v4f acc[4][4];
    const v4f vzero = {0.f, 0.f, 0.f, 0.f};
#pragma unroll
    for (int mt = 0; mt < 4; mt++)
#pragma unroll
        for (int nt = 0; nt < 4; nt++) acc[mt][nt] = vzero;

    __syncthreads();

    // ---- phase 2: barrier-free K loop, only (now L2-hit) B loads in vm queue
#pragma unroll 2
    for (int kb = 0; kb < 16; kb++) {
        v8s af[4], bf[4];
#pragma unroll
        for (int nt = 0; nt < 4; nt++)
            bf[nt] = *((const v8s*)(fb[nt] + kb * 512));
#pragma unroll
        for (int mt = 0; mt < 4; mt++)
            af[mt] = Abuf[(mt * 16 + c) * 64 + ((kb * 4 + q) ^ (c & 7))];
#pragma unroll
        for (int mt = 0; mt < 4; mt++)
#pragma unroll
            for (int nt = 0; nt < 4; nt++)
                acc[mt][nt] = __builtin_amdgcn_mfma_f32_16x16x32_bf16(
                    af[mt], bf[nt], acc[mt][nt], 0, 0, 0);
    }

    // ---- epilogue: bias, LN row stats, normalize, column pool ----
    float pb4[4], lg4[4], lb4[4];
#pragma unroll
    for (int nt = 0; nt < 4; nt++) {
        int n = wv * 64 + nt * 16 + c;
        pb4[nt] = pb[n]; lg4[nt] = lg[n]; lb4[nt] = lb[n];
    }
#pragma unroll
    for (int mt = 0; mt < 4; mt++) {
#pragma unroll
        for (int reg = 0; reg < 4; reg++) {
            float s1 = 0.f, s2 = 0.f;
#pragma unroll
            for (int nt = 0; nt < 4; nt++) {
                float v = acc[mt][nt][reg] + pb4[nt];
                acc[mt][nt][reg] = v;
                s1 += v; s2 += v * v;
            }
#pragma unroll
            for (int d = 1; d < 16; d <<= 1) {
                s1 += __shfl_xor(s1, d);
                s2 += __shfl_xor(s2, d);
            }
            if (c == 0) {
                int r = mt * 16 + q * 4 + reg;
                atomicAdd(&RowS[r], s1);
                atomicAdd(&RowQ[r], s2);
            }
        }
    }
    __syncthreads();
    if (t < 64) {
        float mu = RowS[t] * (1.f / C_);
        float var = RowQ[t] * (1.f / C_) - mu * mu;
        RowS[t] = mu;
        RowQ[t] = rsqrtf(var + 1e-5f);
    }
    __syncthreads();
    float col[4] = {0.f, 0.f, 0.f, 0.f};
#pragma unroll
    for (int mt = 0; mt < 4; mt++) {
#pragma unroll
        for (int reg = 0; reg < 4; reg++) {
            int r = mt * 16 + q * 4 + reg;
            float mu = RowS[r], rs = RowQ[r];
#pragma unroll
            for (int nt = 0; nt < 4; nt++)
                col[nt] += (acc[mt][nt][reg] - mu) * rs * lg4[nt] + lb4[nt];
        }
    }
#pragma unroll
    for (int nt = 0; nt < 4; nt++) {
        col[nt] += __shfl_xor(col[nt], 16);
        col[nt] += __shfl_xor(col[nt], 32);
    }
    if (lane < 16) {
#pragma unroll
        for (int nt = 0; nt < 4; nt++) ColS[wv * 64 + nt * 16 + c] = col[nt];
    }
    __syncthreads();
    atomicAdd(&pooled[b * C_ + t], ColS[t]);
}

// ---- head: single kernel. Each block: redundant h1,h2 (per-thread row dots,
// W1/W2 L2-hot) then a 40-output slice of layer 3 (wave-per-output). ----------
__global__ __launch_bounds__(256)
void head_kernel(const float* __restrict__ pooled,
                 const float* __restrict__ W1, const float* __restrict__ b1,
                 const float* __restrict__ W2, const float* __restrict__ b2,
                 const float* __restrict__ W3, const float* __restrict__ b3,
                 float* __restrict__ out) {
    __shared__ __align__(16) float P[512];
    __shared__ __align__(16) float H1[256];
    __shared__ __align__(16) float H2[256];
    const int t = threadIdx.x, wv = t >> 6, lane = t & 63;
    const int b = blockIdx.x / 25;
    const int slice = blockIdx.x % 25;                 // 25 slices x 40 outputs

    P[t] = pooled[b * C_ + t] * (1.f / 4096.f);
    P[t + 256] = pooled[b * C_ + t + 256] * (1.f / 4096.f);
    __syncthreads();

    // h1[t] = relu(W1[t,:] . P + b1[t])   (128 independent float4 loads)
    {
        const float4* wr = (const float4*)(W1 + t * C_);
        float s = 0.f;
#pragma unroll 8
        for (int k = 0; k < 128; k++) {
            float4 w = wr[k];
            float4 p = ((const float4*)P)[k];
            s += w.x * p.x + w.y * p.y + w.z * p.z + w.w * p.w;
        }
        H1[t] = fmaxf(s + b1[t], 0.f);
    }
    __syncthreads();

    // h2[t] = relu(W2[t,:] . H1 + b2[t])
    {
        const float4* wr = (const float4*)(W2 + t * H_);
        float s = 0.f;
#pragma unroll 8
        for (int k = 0; k < 64; k++) {
            float4 w = wr[k];
            float4 p = ((const float4*)H1)[k];
            s += w.x * p.x + w.y * p.y + w.z * p.z + w.w * p.w;
        }
        H2[t] = fmaxf(s + b2[t], 0.f);
    }
    __syncthreads();

    // layer 3: this block's 40 outputs, wave-per-output (coalesced W3 row)
#pragma unroll
    for (int jj = 0; jj < 10; jj++) {
        const int o = slice * 40 + jj * 4 + wv;
        float4 w = ((const float4*)(W3 + o * H_))[lane];
        float4 p = ((const float4*)H2)[lane];
        float s = w.x * p.x + w.y * p.y + w.z * p.z + w.w * p.w;
#pragma unroll
        for (int d = 1; d < 64; d <<= 1) s += __shfl_xor(s, d);
        if (lane == 0) out[b * NC_ + o] = s + b3[o];
    }
}

extern "C" void kernel_launch(void* const* d_in, const int* in_sizes, int n_in,
                              void* d_out, int out_size, void* d_ws, size_t ws_size,
                              hipStream_t stream) {
    const float* feat  = (const float*)d_in[0];
    const float* prev  = (const float*)d_in[1];
    // d_in[2] = pos_org (implicit: key(pos_org[n]) == n) — unused
    const float* ps    = (const float*)d_in[3];
    const float* projW = (const float*)d_in[4];
    const float* pb    = (const float*)d_in[5];
    const float* lg    = (const float*)d_in[6];
    const float* lb    = (const float*)d_in[7];
    const float* W1    = (const float*)d_in[8];
    const float* b1    = (const float*)d_in[9];
    const float* W2    = (const float*)d_in[10];
    const float* b2    = (const float*)d_in[11];
    const float* W3    = (const float*)d_in[12];
    const float* b3    = (const float*)d_in[13];
    float* out = (float*)d_out;

    char* ws = (char*)d_ws;
    ushort_t* Wfrag = (ushort_t*)ws;                     // 524288 B (exact)
    int* inv        = (int*)(ws + 524288);               // 131072 B
    float* pooled   = (float*)(ws + 655360);             // 16384 B

    prep_kernel<<<256, 256, 0, stream>>>(ps, projW, inv, Wfrag, pooled);
    gemm_ln_pool<<<768, 512, 0, stream>>>(feat, prev, inv, Wfrag,
                                          pb, lg, lb, pooled);
    head_kernel<<<200, 256, 0, stream>>>(pooled, W1, b1, W2, b2, W3, b3, out);
}